// Round 2
// baseline (709.045 us; speedup 1.0000x reference)
//
#include <hip/hip_runtime.h>
#include <cstdint>
#include <cstddef>

typedef unsigned short u16;
typedef __bf16 bf16x8 __attribute__((ext_vector_type(8)));
typedef unsigned short u16x8 __attribute__((ext_vector_type(8)));
typedef float   f32x4 __attribute__((ext_vector_type(4)));

#define D_MODEL 1024
#define NF      256      // num random features (M)
#define DEPTH   512
#define SEQ     4096
#define ROWS    16384    // B*L = 4*4096
#define HROWS   32768    // ROWS * NUM_HEADS (Q viewed as 32768 x 512)

// scale = 512^-0.25 ; folded into proj. 0.5*scale^2 used for diag.
#define QK_SCALE      0.21022410381342864f
#define HALF_SCALE2   0.022097086912079608f

__device__ __forceinline__ u16 f2bf(float f) {
  union { float f; uint32_t u; } x; x.f = f;
  uint32_t r = x.u + 0x7FFFu + ((x.u >> 16) & 1u);
  return (u16)(r >> 16);
}
__device__ __forceinline__ float bf2f(u16 u) {
  union { uint32_t u; float f; } x; x.u = ((uint32_t)u) << 16;
  return x.f;
}

// async global->LDS, 16B per lane; LDS dest = wave-uniform base + lane*16B.
__device__ __forceinline__ void gload16(const u16* g, u16* l) {
  __builtin_amdgcn_global_load_lds((const __attribute__((address_space(1))) void*)g,
                                   (__attribute__((address_space(3))) void*)l,
                                   16, 0, 0);
}

// ---------------- weight prep kernels ----------------

// W (1024x1024 f32) -> W^T bf16 ([N][K] layout for gemm_bt). blockIdx.z picks matrix.
__global__ void transpose4_kernel(const float* __restrict__ w0, const float* __restrict__ w1,
                                  const float* __restrict__ w2, const float* __restrict__ w3,
                                  u16* __restrict__ o0, u16* __restrict__ o1,
                                  u16* __restrict__ o2, u16* __restrict__ o3) {
  __shared__ float tile[32][33];
  int z = blockIdx.z;
  const float* src = (z == 0) ? w0 : (z == 1) ? w1 : (z == 2) ? w2 : w3;
  u16* dst         = (z == 0) ? o0 : (z == 1) ? o1 : (z == 2) ? o2 : o3;
  int bx = blockIdx.x * 32, by = blockIdx.y * 32;
  int tx = threadIdx.x, ty = threadIdx.y;  // block (32,8)
#pragma unroll
  for (int r = ty; r < 32; r += 8) tile[r][tx] = src[(size_t)(by + r) * D_MODEL + bx + tx];
  __syncthreads();
#pragma unroll
  for (int r = ty; r < 32; r += 8)
    dst[(size_t)(bx + r) * D_MODEL + by + tx] = f2bf(tile[tx][r]);
}

// proj (256x512 f32) -> bf16 with qk scale folded in. 32768 threads, 4 elems each.
__global__ void projcvt_kernel(const float4* __restrict__ p, ushort4* __restrict__ o) {
  int i = blockIdx.x * 256 + threadIdx.x;
  float4 a = p[i];
  o[i] = make_ushort4(f2bf(a.x * QK_SCALE), f2bf(a.y * QK_SCALE),
                      f2bf(a.z * QK_SCALE), f2bf(a.w * QK_SCALE));
}

// ---------------- GEMM: C[M][N] = A[M][K] @ B[N][K]^T + bias ----------------
// 128x128 tile, BK=32, 256 threads = 4 waves in 2x2 grid, each wave 64x64 via
// 4x4 mfma_f32_16x16x32_bf16.
//
// COUNTED-VMCNT SCHEDULE (T4): raw s_barriers, never drain vmcnt(0) in-loop.
// Tile t+2 is issued right after barrier#2 of iter t (the barrier that proves
// all waves retired their fragment ds_reads of buffer buf=t&1), targeting that
// same buffer. Every staging load thus has ~2 iterations in flight before its
// wait. The asm "memory" clobbers delimit issue REGIONS; inter-region vmem
// FIFO order is strict, so a counted wait of (ops-per-region) at barrier#1
// retires exactly the tile-t region regardless of intra-region scheduling:
//   - bf16-A path: s_waitcnt vmcnt(4)   (region = 4 LDS-DMA ops)
//   - fp32-A path: s_waitcnt vmcnt(6)   (region = 2 B LDS-DMA + 4 A float4)
// Prologue's two issue groups are separated by a zero-cost compiler memory
// fence to pin the same region structure.
// Tail: clamped re-issue tp=min(t+2,T-1) keeps wait counts uniform; re-DMA of
// identical bytes into a dead or identical buffer is benign. Final vmcnt(0)
// drains LDS-DMA before the epilogue/endpgm.
// Loop is 2x-unrolled with named pA*/pB* regs (no runtime-indexed reg arrays).
//
// LDS chunk swizzle: tile row stride is 64 B, so identity placement makes
// b128 reads 8-way bank-conflicted. Lane l stages global chunk
// c = ((l&3)-(l>>3))&3 of row l>>2 into dense slot l (DMA-compatible);
// reads use slot (quad + (l15>>1))&3 -> exactly 2 lanes/bank-group (free).
//
// Multi-source fusion: bm >= mtiles selects source z (A/B/C/bias per z) —
// QKV runs as ONE dispatch (grid 384x8), the two feature GEMMs as one
// (grid 512x2). XCD locality: linear = bm + gridDim.x*bn with gridDim.x a
// multiple of 8, so all bn-blocks sharing an A-panel land on one XCD.
template <bool BF16OUT, bool AFP32>
__global__ __launch_bounds__(256) void gemm_bt_kernel(
    const void* __restrict__ Av0, const void* __restrict__ Av1, const void* __restrict__ Av2,
    const u16* __restrict__ B0, const u16* __restrict__ B1, const u16* __restrict__ B2,
    void* __restrict__ Cv0, void* __restrict__ Cv1, void* __restrict__ Cv2,
    const float* __restrict__ bias0, const float* __restrict__ bias1,
    const float* __restrict__ bias2, int K, int N, int mtiles) {
  __shared__ __align__(16) u16 As[2][128 * 32];
  __shared__ __align__(16) u16 Bs[2][128 * 32];
  const int tid  = threadIdx.x;
  const int lane = tid & 63;
  const int wave = tid >> 6;
  const int wm = wave >> 1, wn = wave & 1;
  const int quad = lane >> 4, l15 = lane & 15;
  int bm = blockIdx.x;
  const int bn = blockIdx.y;
  int z = 0;
  while (bm >= mtiles) { bm -= mtiles; z++; }   // <=2 iterations, SALU
  const void*  Av   = (z == 0) ? Av0 : (z == 1) ? Av1 : Av2;
  const u16*   B    = (z == 0) ? B0  : (z == 1) ? B1  : B2;
  void*        Cv   = (z == 0) ? Cv0 : (z == 1) ? Cv1 : Cv2;
  const float* bias = (z == 0) ? bias0 : (z == 1) ? bias1 : bias2;

  const int srow   = lane >> 2;
  const int schunk = ((lane & 3) - (lane >> 3)) & 3;   // swizzled chunk for lane
  const int scol   = schunk * 8;

  const u16* Bb  = B + (size_t)bn * 128 * K;
  const u16* Bg0 = Bb + (size_t)(wave * 32 + srow) * K + scol;
  const u16* Bg1 = Bg0 + (size_t)16 * K;

  const float* Af0 = nullptr; const float* Af1 = nullptr;
  const u16*   Ag0 = nullptr; const u16*   Ag1 = nullptr;
  if (AFP32) {
    const float* Ab = (const float*)Av + (size_t)bm * 128 * K;
    Af0 = Ab + (size_t)(wave * 32 + srow) * K + scol;
    Af1 = Af0 + (size_t)16 * K;
  } else {
    const u16* Ab = (const u16*)Av + (size_t)bm * 128 * K;
    Ag0 = Ab + (size_t)(wave * 32 + srow) * K + scol;
    Ag1 = Ag0 + (size_t)16 * K;
  }

  const int wbase  = wave * 1024;          // dense wave slot (u16 units)
  const int sslot0 = wbase + lane * 8;
  const int sslot1 = sslot0 + 512;
  // swizzled read offset within a 16-row group (u16 units)
  const int ro = l15 * 32 + (((quad + (l15 >> 1)) & 3) * 8);

  f32x4 acc[4][4] = {};
  float4 pA0, pA1, pA2, pA3, pB0, pB1, pB2, pB3;

  const int T = K >> 5;   // always even (K = 512 or 1024)

  // ---- prologue: stage tiles 0 and 1 (B DMA before A loads per batch) ----
  if (AFP32) {
    gload16(Bg0, &Bs[0][wbase]);
    gload16(Bg1, &Bs[0][wbase + 512]);
    pA0 = *(const float4*)(Af0);
    pA1 = *(const float4*)(Af0 + 4);
    pA2 = *(const float4*)(Af1);
    pA3 = *(const float4*)(Af1 + 4);
    asm volatile("" ::: "memory");   // region boundary: tile-0 issues | tile-1 issues
    gload16(Bg0 + 32, &Bs[1][wbase]);
    gload16(Bg1 + 32, &Bs[1][wbase + 512]);
    pB0 = *(const float4*)(Af0 + 32);
    pB1 = *(const float4*)(Af0 + 36);
    pB2 = *(const float4*)(Af1 + 32);
    pB3 = *(const float4*)(Af1 + 36);
  } else {
    gload16(Ag0, &As[0][wbase]);
    gload16(Ag1, &As[0][wbase + 512]);
    gload16(Bg0, &Bs[0][wbase]);
    gload16(Bg1, &Bs[0][wbase + 512]);
    asm volatile("" ::: "memory");   // region boundary
    gload16(Ag0 + 32, &As[1][wbase]);
    gload16(Ag1 + 32, &As[1][wbase + 512]);
    gload16(Bg0 + 32, &Bs[1][wbase]);
    gload16(Bg1 + 32, &Bs[1][wbase + 512]);
  }

#define GEMM_STEP(BUF, TT, P0, P1, P2, P3)                                     \
  {                                                                            \
    if (AFP32) {                                                               \
      u16x8 c0, c1;                                                            \
      c0[0] = f2bf(P0.x); c0[1] = f2bf(P0.y); c0[2] = f2bf(P0.z); c0[3] = f2bf(P0.w); \
      c0[4] = f2bf(P1.x); c0[5] = f2bf(P1.y); c0[6] = f2bf(P1.z); c0[7] = f2bf(P1.w); \
      c1[0] = f2bf(P2.x); c1[1] = f2bf(P2.y); c1[2] = f2bf(P2.z); c1[3] = f2bf(P2.w); \
      c1[4] = f2bf(P3.x); c1[5] = f2bf(P3.y); c1[6] = f2bf(P3.z); c1[7] = f2bf(P3.w); \
      *(u16x8*)&As[BUF][sslot0] = c0;                                          \
      *(u16x8*)&As[BUF][sslot1] = c1;                                          \
      /* vmcnt(6): retires the tile-TT issue region (2 B-DMA + 4 A-loads);     \
         lgkmcnt(0): my ds_writes of A visible before the barrier. */          \
      asm volatile("s_waitcnt vmcnt(6) lgkmcnt(0)\n\ts_barrier" ::: "memory"); \
    } else {                                                                   \
      /* vmcnt(4): exactly one 4-op region (tile TT+1) left in flight */       \
      asm volatile("s_waitcnt vmcnt(4)\n\ts_barrier" ::: "memory");            \
    }                                                                          \
    bf16x8 af[4], bfr[4];                                                      \
    _Pragma("unroll")                                                          \
    for (int mt = 0; mt < 4; mt++)                                             \
      af[mt] = *(const bf16x8*)&As[BUF][(wm * 4 + mt) * 512 + ro];             \
    _Pragma("unroll")                                                          \
    for (int nt = 0; nt < 4; nt++)                                             \
      bfr[nt] = *(const bf16x8*)&Bs[BUF][(wn * 4 + nt) * 512 + ro];            \
    /* my fragment reads retired -> safe for anyone to overwrite buf after */  \
    asm volatile("s_waitcnt lgkmcnt(0)\n\ts_barrier" ::: "memory");            \
    const int tp = ((TT) + 2 < T) ? (TT) + 2 : T - 1;                          \
    const int kp = tp << 5;                                                    \
    if (AFP32) {                                                               \
      gload16(Bg0 + kp, &Bs[BUF][wbase]);                                      \
      gload16(Bg1 + kp, &Bs[BUF][wbase + 512]);                                \
      P0 = *(const float4*)(Af0 + kp);                                         \
      P1 = *(const float4*)(Af0 + kp + 4);                                     \
      P2 = *(const float4*)(Af1 + kp);                                         \
      P3 = *(const float4*)(Af1 + kp + 4);                                     \
    } else {                                                                   \
      gload16(Ag0 + kp, &As[BUF][wbase]);                                      \
      gload16(Ag1 + kp, &As[BUF][wbase + 512]);                                \
      gload16(Bg0 + kp, &Bs[BUF][wbase]);                                      \
      gload16(Bg1 + kp, &Bs[BUF][wbase + 512]);                                \
    }                                                                          \
    _Pragma("unroll")                                                          \
    for (int mt = 0; mt < 4; mt++)                                             \
      _Pragma("unroll")                                                        \
      for (int nt = 0; nt < 4; nt++)                                           \
        acc[mt][nt] = __builtin_amdgcn_mfma_f32_16x16x32_bf16(af[mt], bfr[nt], \
                                                              acc[mt][nt], 0, 0, 0); \
  }

  for (int t = 0; t < T; t += 2) {
    GEMM_STEP(0, t,     pA0, pA1, pA2, pA3)
    GEMM_STEP(1, t + 1, pB0, pB1, pB2, pB3)
  }
#undef GEMM_STEP

  // drain in-flight LDS-DMA (tail re-issues) before LDS dealloc / endpgm
  asm volatile("s_waitcnt vmcnt(0)" ::: "memory");

  // epilogue: C/D layout col = lane&15, row = quad*4 + reg  [m89/m91 verified]
  const int rbase = bm * 128 + wm * 64 + quad * 4;
  const int cbase = bn * 128 + wn * 64 + l15;
#pragma unroll
  for (int nt = 0; nt < 4; nt++) {
    int col = cbase + nt * 16;
    float bvad = bias ? bias[col] : 0.0f;
#pragma unroll
    for (int mt = 0; mt < 4; mt++) {
#pragma unroll
      for (int r = 0; r < 4; r++) {
        int row = rbase + mt * 16 + r;
        float v = acc[mt][nt][r] + bvad;
        if (BF16OUT) ((u16*)Cv)[(size_t)row * N + col] = f2bf(v);
        else         ((float*)Cv)[(size_t)row * N + col] = v;
      }
    }
  }
}

// ---------------- diag: 0.5*scale^2*||row||^2 over Qb/Kb rows of 512 ----------------
// grid 16384 x 256: 4 waves/block, one row per wave; rows 0..32767 -> Q, 32768.. -> K.
__global__ void diag_kernel(const u16* __restrict__ Qb, const u16* __restrict__ Kb,
                            float* __restrict__ dq, float* __restrict__ dk) {
  const int wave = threadIdx.x >> 6, lane = threadIdx.x & 63;
  int row = blockIdx.x * 4 + wave;
  const u16* src; float* dst; int r;
  if (row < HROWS) { src = Qb; dst = dq; r = row; }
  else             { src = Kb; dst = dk; r = row - HROWS; }
  const ushort4* p = (const ushort4*)(src + (size_t)r * DEPTH);
  ushort4 u0 = p[lane * 2], u1 = p[lane * 2 + 1];
  float s = 0.f, f;
  f = bf2f(u0.x); s += f * f; f = bf2f(u0.y); s += f * f;
  f = bf2f(u0.z); s += f * f; f = bf2f(u0.w); s += f * f;
  f = bf2f(u1.x); s += f * f; f = bf2f(u1.y); s += f * f;
  f = bf2f(u1.z); s += f * f; f = bf2f(u1.w); s += f * f;
#pragma unroll
  for (int o = 32; o; o >>= 1) s += __shfl_xor(s, o);
  if (lane == 0) dst[r] = s * HALF_SCALE2;
}

// ---------------- global max of k_dash per (batch,head) ----------------
// stage 1: grid 512 = 8 groups * 64 s-blocks (64 s each); one partial per block.
__global__ void maxk_part_kernel(const float* __restrict__ kd, float* __restrict__ partials) {
  int g = blockIdx.x >> 6;   // b*2+h
  int sb = blockIdx.x & 63;
  int b = g >> 1, h = g & 1;
  int tid = threadIdx.x;
  float mx = -3.4e38f;
  for (int j = 0; j < 64; j++) {
    int s = sb * 64 + j;
    int row = b * 8192 + s * 2 + h;
    mx = fmaxf(mx, kd[(size_t)row * NF + tid]);
  }
#pragma unroll
  for (int o = 32; o; o >>= 1) mx = fmaxf(mx, __shfl_xor(mx, o));
  __shared__ float wmax[4];
  if ((tid & 63) == 0) wmax[tid >> 6] = mx;
  __syncthreads();
  if (tid == 0)
    partials[blockIdx.x] = fmaxf(fmaxf(wmax[0], wmax[1]), fmaxf(wmax[2], wmax[3]));
}

// stage 2: 8 blocks x 64 lanes.
__global__ void maxk_final_kernel(const float* __restrict__ partials, float* __restrict__ mxk) {
  float v = partials[blockIdx.x * 64 + threadIdx.x];
#pragma unroll
  for (int o = 32; o; o >>= 1) v = fmaxf(v, __shfl_xor(v, o));
  if (threadIdx.x == 0) mxk[blockIdx.x] = v;
}

// ---------------- fused exp + 4x4 batch-contraction attention ----------------
// One block per (s,h). q',k' via online exp; A = q'k'^T (4x4); out = (A@v)/rowsum(A).
// Writes concat bf16 at flat s*4096 + h*2048 + batch*512 + d (the reshape quirk).
__global__ __launch_bounds__(256) void attn_kernel(
    const float* __restrict__ qd, const float* __restrict__ kd,
    const float* __restrict__ diagq, const float* __restrict__ diagk,
    const float* __restrict__ mxk, const u16* __restrict__ Vb,
    u16* __restrict__ concat) {
  int s = blockIdx.x >> 1, h = blockIdx.x & 1;
  int t = threadIdx.x;           // 256 threads; thread t <-> feature m = t
  int wave = t >> 6, lane = t & 63;
  __shared__ float qp[4][256], kp[4][256];
  __shared__ float As[4][4];
  __shared__ float wred[4][4];   // [wave][b]
  __shared__ float mqs[4];

  float qv[4], kv[4];
  int rows[4];
#pragma unroll
  for (int b = 0; b < 4; b++) {
    int r = b * 8192 + s * 2 + h;
    rows[b] = r;
    qv[b] = qd[(size_t)r * NF + t];
    kv[b] = kd[(size_t)r * NF + t];
  }
  // per-row max of q_dash (max over m == over the 256 threads)
#pragma unroll
  for (int b = 0; b < 4; b++) {
    float v = qv[b];
#pragma unroll
    for (int o = 32; o; o >>= 1) v = fmaxf(v, __shfl_xor(v, o));
    if (lane == 0) wred[wave][b] = v;
  }
  __syncthreads();
  if (t < 4) mqs[t] = fmaxf(fmaxf(wred[0][t], wred[1][t]), fmaxf(wred[2][t], wred[3][t]));
  __syncthreads();
#pragma unroll
  for (int b = 0; b < 4; b++) {
    qp[b][t] = __expf(qv[b] - diagq[rows[b]] - mqs[b]) + 1e-6f;
    kp[b][t] = __expf(kv[b] - diagk[rows[b]] - mxk[b * 2 + h]) + 1e-6f;
  }
  __syncthreads();
  // A[i][j] = sum_m qp[i][m]*kp[j][m]; wave i computes row i.
  {
    int i = wave;
    float p0 = 0, p1 = 0, p2 = 0, p3 = 0;
    for (int m = lane; m < 256; m += 64) {
      float q = qp[i][m];
      p0 += q * kp[0][m]; p1 += q * kp[1][m];
      p2 += q * kp[2][m]; p3 += q * kp[3][m];
    }
#pragma unroll
    for (int o = 32; o; o >>= 1) {
      p0 += __shfl_xor(p0, o); p1 += __shfl_xor(p1, o);
      p2 += __shfl_xor(p2, o); p3 += __shfl_xor(p3, o);
    }
    if (lane == 0) { As[i][0] = p0; As[i][1] = p1; As[i][2] = p2; As[i][3] = p3; }
  }
  __syncthreads();
  float a00 = As[0][0], a01 = As[0][1], a02 = As[0][2], a03 = As[0][3];
  float a10 = As[1][0], a11 = As[1][1], a12 = As[1][2], a13 = As[1][3];
  float a20 = As[2][0], a21 = As[2][1], a22 = As[2][2], a23 = As[2][3];
  float a30 = As[3][0], a31 = As[3][1], a32 = As[3][2], a33 = As[3][3];
  float n0 = 1.f / (a00 + a01 + a02 + a03);
  float n1 = 1.f / (a10 + a11 + a12 + a13);
  float n2 = 1.f / (a20 + a21 + a22 + a23);
  float n3 = 1.f / (a30 + a31 + a32 + a33);
  size_t obase = (size_t)s * 4096 + (size_t)h * 2048;
#pragma unroll
  for (int dp = 0; dp < 2; dp++) {
    int d = t + dp * 256;
    float v0 = bf2f(Vb[((size_t)(0 * SEQ + s)) * D_MODEL + h * DEPTH + d]);
    float v1 = bf2f(Vb[((size_t)(1 * SEQ + s)) * D_MODEL + h * DEPTH + d]);
    float v2 = bf2f(Vb[((size_t)(2 * SEQ + s)) * D_MODEL + h * DEPTH + d]);
    float v3 = bf2f(Vb[((size_t)(3 * SEQ + s)) * D_MODEL + h * DEPTH + d]);
    concat[obase + 0 * 512 + d] = f2bf((a00 * v0 + a01 * v1 + a02 * v2 + a03 * v3) * n0);
    concat[obase + 1 * 512 + d] = f2bf((a10 * v0 + a11 * v1 + a12 * v2 + a13 * v3) * n1);
    concat[obase + 2 * 512 + d] = f2bf((a20 * v0 + a21 * v1 + a22 * v2 + a23 * v3) * n2);
    concat[obase + 3 * 512 + d] = f2bf((a30 * v0 + a31 * v1 + a32 * v2 + a33 * v3) * n3);
  }
}

// ---------------- launch ----------------
extern "C" void kernel_launch(void* const* d_in, const int* in_sizes, int n_in,
                              void* d_out, int out_size, void* d_ws, size_t ws_size,
                              hipStream_t stream) {
  (void)in_sizes; (void)n_in; (void)out_size; (void)ws_size;
  const float* query = (const float*)d_in[0];
  const float* key   = (const float*)d_in[1];
  const float* value = (const float*)d_in[2];
  // d_in[3] = mask (unused by the reference computation)
  const float* Wq = (const float*)d_in[4];
  const float* bq = (const float*)d_in[5];
  const float* Wk = (const float*)d_in[6];
  const float* bk = (const float*)d_in[7];
  const float* Wv = (const float*)d_in[8];
  const float* bv = (const float*)d_in[9];
  const float* Wo = (const float*)d_in[10];
  const float* bo = (const float*)d_in[11];
  const float* proj = (const float*)d_in[12];
  float* out = (float*)d_out;

  char* w = (char*)d_ws;
  size_t o = 0;
  auto take = [&](size_t b) { void* p = w + o; o += (b + 255) & ~(size_t)255; return p; };
  u16* Wqt   = (u16*)take(2097152);
  u16* Wkt   = (u16*)take(2097152);
  u16* Wvt   = (u16*)take(2097152);
  u16* Wot   = (u16*)take(2097152);
  u16* projb = (u16*)take(262144);
  u16* Qb    = (u16*)take(33554432);    // 32768 x 512 bf16
  u16* Kb    = (u16*)take(33554432);
  u16* Vb    = (u16*)take(33554432);
  float* qd  = (float*)take(33554432);  // 32768 x 256 f32
  float* kd  = (float*)take(33554432);
  u16* concat = (u16*)take(33554432);   // 16384 x 1024 bf16
  float* diagq    = (float*)take(131072);
  float* diagk    = (float*)take(131072);
  float* partials = (float*)take(2048);
  float* mxk      = (float*)take(64);
  // peak ws use ~201 MB

  transpose4_kernel<<<dim3(32, 32, 4), dim3(32, 8), 0, stream>>>(Wq, Wk, Wv, Wo,
                                                                 Wqt, Wkt, Wvt, Wot);
  projcvt_kernel<<<128, 256, 0, stream>>>((const float4*)proj, (ushort4*)projb);

  // QKV projections fused into ONE dispatch (z = bm/128 selects q/k/v).
  gemm_bt_kernel<true, true><<<dim3(384, 8), 256, 0, stream>>>(
      query, key, value, Wqt, Wkt, Wvt, Qb, Kb, Vb, bq, bk, bv, 1024, 1024, 128);

  diag_kernel<<<16384, 256, 0, stream>>>(Qb, Kb, diagq, diagk);

  // feature projections fused into ONE dispatch (z = bm/256 selects Qb/Kb).
  gemm_bt_kernel<false, false><<<dim3(512, 2), 256, 0, stream>>>(
      Qb, Kb, nullptr, projb, projb, nullptr, qd, kd, nullptr,
      nullptr, nullptr, nullptr, 512, 256, 256);

  maxk_part_kernel<<<512, 256, 0, stream>>>(kd, partials);
  maxk_final_kernel<<<8, 64, 0, stream>>>(partials, mxk);

  attn_kernel<<<8192, 256, 0, stream>>>(qd, kd, diagq, diagk, mxk, Vb, concat);

  gemm_bt_kernel<false, false><<<dim3(128, 8), 256, 0, stream>>>(
      concat, nullptr, nullptr, Wot, nullptr, nullptr, out, nullptr, nullptr,
      bo, nullptr, nullptr, 1024, 1024, 128);
}

// Round 3
// 700.523 us; speedup vs baseline: 1.0122x; 1.0122x over previous
//
#include <hip/hip_runtime.h>
#include <cstdint>
#include <cstddef>

typedef unsigned short u16;
typedef __bf16 bf16x8 __attribute__((ext_vector_type(8)));
typedef unsigned short u16x8 __attribute__((ext_vector_type(8)));
typedef float   f32x4 __attribute__((ext_vector_type(4)));

#define D_MODEL 1024
#define NF      256      // num random features (M)
#define DEPTH   512
#define SEQ     4096
#define ROWS    16384    // B*L = 4*4096
#define HROWS   32768    // ROWS * NUM_HEADS (Q viewed as 32768 x 512)

// scale = 512^-0.25 ; folded into proj. 0.5*scale^2 used for diag.
#define QK_SCALE      0.21022410381342864f
#define HALF_SCALE2   0.022097086912079608f

__device__ __forceinline__ u16 f2bf(float f) {
  union { float f; uint32_t u; } x; x.f = f;
  uint32_t r = x.u + 0x7FFFu + ((x.u >> 16) & 1u);
  return (u16)(r >> 16);
}
__device__ __forceinline__ float bf2f(u16 u) {
  union { uint32_t u; float f; } x; x.u = ((uint32_t)u) << 16;
  return x.f;
}

// async global->LDS, 16B per lane; LDS dest = wave-uniform base + lane*16B.
__device__ __forceinline__ void gload16(const u16* g, u16* l) {
  __builtin_amdgcn_global_load_lds((const __attribute__((address_space(1))) void*)g,
                                   (__attribute__((address_space(3))) void*)l,
                                   16, 0, 0);
}

// ---------------- weight prep kernels ----------------

// W (1024x1024 f32) -> W^T bf16 ([N][K] layout for gemm_bt). blockIdx.z picks matrix.
__global__ void transpose4_kernel(const float* __restrict__ w0, const float* __restrict__ w1,
                                  const float* __restrict__ w2, const float* __restrict__ w3,
                                  u16* __restrict__ o0, u16* __restrict__ o1,
                                  u16* __restrict__ o2, u16* __restrict__ o3) {
  __shared__ float tile[32][33];
  int z = blockIdx.z;
  const float* src = (z == 0) ? w0 : (z == 1) ? w1 : (z == 2) ? w2 : w3;
  u16* dst         = (z == 0) ? o0 : (z == 1) ? o1 : (z == 2) ? o2 : o3;
  int bx = blockIdx.x * 32, by = blockIdx.y * 32;
  int tx = threadIdx.x, ty = threadIdx.y;  // block (32,8)
#pragma unroll
  for (int r = ty; r < 32; r += 8) tile[r][tx] = src[(size_t)(by + r) * D_MODEL + bx + tx];
  __syncthreads();
#pragma unroll
  for (int r = ty; r < 32; r += 8)
    dst[(size_t)(bx + r) * D_MODEL + by + tx] = f2bf(tile[tx][r]);
}

// proj (256x512 f32) -> bf16 with qk scale folded in. 32768 threads, 4 elems each.
__global__ void projcvt_kernel(const float4* __restrict__ p, ushort4* __restrict__ o) {
  int i = blockIdx.x * 256 + threadIdx.x;
  float4 a = p[i];
  o[i] = make_ushort4(f2bf(a.x * QK_SCALE), f2bf(a.y * QK_SCALE),
                      f2bf(a.z * QK_SCALE), f2bf(a.w * QK_SCALE));
}

// ---------------- GEMM: C[M][N] = A[M][K] @ B[N][K]^T + bias ----------------
// 128x128 tile, BK=32, 256 threads = 4 waves in 2x2 grid, each wave 64x64 via
// 4x4 mfma_f32_16x16x32_bf16.
//
// COUNTED-VMCNT SCHEDULE (T4): raw s_barriers, never drain vmcnt(0) in-loop.
// Tile t+2 is issued right after barrier#2 of iter t, targeting the buffer
// just released by the fragment ds_reads. Counted waits at barrier#1 retire
// exactly the tile-t issue region (asm "memory" clobbers pin region order):
//   - bf16-A path: s_waitcnt vmcnt(4)   (region = 4 LDS-DMA ops)
//   - fp32-A path: s_waitcnt vmcnt(6)   (region = 2 B LDS-DMA + 4 A float4)
// Tail: clamped re-issue tp=min(t+2,T-1) — re-reads L2-hot bytes, benign.
// Final vmcnt(0) drains LDS-DMA before the epilogue.
//
// XCD-CLUSTERED BLOCK REMAP (round-2 post-mortem): HW round-robins XCDs by
// flat linear id (xcd = l % 8). Remap so the NT bn-blocks sharing one
// A-panel are (a) on the SAME XCD and (b) ADJACENT in dispatch order:
//   x = l & 7; q = l >> 3; bn = q & (NT-1); bm = (q >> log2(NT)) * 8 + x.
// Bijective when MT % 8 == 0 (384/512/128 all ok). Per XCD, bn cycles
// fastest -> A-panel sharers co-resident (span 64 linear), and only one z's
// B matrix (2 MB) is live per XCD at a time (fits 4 MB L2). Round 2's fused
// grid without this remap thrashed L2: FETCH 794 MB vs ~240 MB ideal.
//
// LDS chunk swizzle: tile row stride is 64 B, so identity placement makes
// b128 reads 8-way bank-conflicted. Lane l stages global chunk
// c = ((l&3)-(l>>3))&3 of row l>>2 into dense slot l (DMA-compatible);
// reads use slot (quad + (l15>>1))&3 -> exactly 2 lanes/bank-group (free).
//
// Multi-source fusion: bm >= mtiles selects source z (A/B/C/bias per z) —
// QKV runs as ONE dispatch (grid 384x8), the two feature GEMMs as one
// (grid 512x2).
template <bool BF16OUT, bool AFP32>
__global__ __launch_bounds__(256) void gemm_bt_kernel(
    const void* __restrict__ Av0, const void* __restrict__ Av1, const void* __restrict__ Av2,
    const u16* __restrict__ B0, const u16* __restrict__ B1, const u16* __restrict__ B2,
    void* __restrict__ Cv0, void* __restrict__ Cv1, void* __restrict__ Cv2,
    const float* __restrict__ bias0, const float* __restrict__ bias1,
    const float* __restrict__ bias2, int K, int N, int mtiles, int lognt) {
  __shared__ __align__(16) u16 As[2][128 * 32];
  __shared__ __align__(16) u16 Bs[2][128 * 32];
  const int tid  = threadIdx.x;
  const int lane = tid & 63;
  const int wave = tid >> 6;
  const int wm = wave >> 1, wn = wave & 1;
  const int quad = lane >> 4, l15 = lane & 15;

  // XCD-clustered remap (see header comment)
  const int l = blockIdx.x + gridDim.x * blockIdx.y;
  const int xcd = l & 7;
  const int q8  = l >> 3;
  const int bn  = q8 & ((1 << lognt) - 1);
  int bm        = ((q8 >> lognt) << 3) + xcd;

  int z = 0;
  while (bm >= mtiles) { bm -= mtiles; z++; }   // <=2 iterations, SALU
  const void*  Av   = (z == 0) ? Av0 : (z == 1) ? Av1 : Av2;
  const u16*   B    = (z == 0) ? B0  : (z == 1) ? B1  : B2;
  void*        Cv   = (z == 0) ? Cv0 : (z == 1) ? Cv1 : Cv2;
  const float* bias = (z == 0) ? bias0 : (z == 1) ? bias1 : bias2;

  const int srow   = lane >> 2;
  const int schunk = ((lane & 3) - (lane >> 3)) & 3;   // swizzled chunk for lane
  const int scol   = schunk * 8;

  const u16* Bb  = B + (size_t)bn * 128 * K;
  const u16* Bg0 = Bb + (size_t)(wave * 32 + srow) * K + scol;
  const u16* Bg1 = Bg0 + (size_t)16 * K;

  const float* Af0 = nullptr; const float* Af1 = nullptr;
  const u16*   Ag0 = nullptr; const u16*   Ag1 = nullptr;
  if (AFP32) {
    const float* Ab = (const float*)Av + (size_t)bm * 128 * K;
    Af0 = Ab + (size_t)(wave * 32 + srow) * K + scol;
    Af1 = Af0 + (size_t)16 * K;
  } else {
    const u16* Ab = (const u16*)Av + (size_t)bm * 128 * K;
    Ag0 = Ab + (size_t)(wave * 32 + srow) * K + scol;
    Ag1 = Ag0 + (size_t)16 * K;
  }

  const int wbase  = wave * 1024;          // dense wave slot (u16 units)
  const int sslot0 = wbase + lane * 8;
  const int sslot1 = sslot0 + 512;
  // swizzled read offset within a 16-row group (u16 units)
  const int ro = l15 * 32 + (((quad + (l15 >> 1)) & 3) * 8);

  f32x4 acc[4][4] = {};
  float4 pA0, pA1, pA2, pA3, pB0, pB1, pB2, pB3;

  const int T = K >> 5;   // always even (K = 512 or 1024)

  // ---- prologue: stage tiles 0 and 1 (B DMA before A loads per batch) ----
  if (AFP32) {
    gload16(Bg0, &Bs[0][wbase]);
    gload16(Bg1, &Bs[0][wbase + 512]);
    pA0 = *(const float4*)(Af0);
    pA1 = *(const float4*)(Af0 + 4);
    pA2 = *(const float4*)(Af1);
    pA3 = *(const float4*)(Af1 + 4);
    asm volatile("" ::: "memory");   // region boundary: tile-0 issues | tile-1 issues
    gload16(Bg0 + 32, &Bs[1][wbase]);
    gload16(Bg1 + 32, &Bs[1][wbase + 512]);
    pB0 = *(const float4*)(Af0 + 32);
    pB1 = *(const float4*)(Af0 + 36);
    pB2 = *(const float4*)(Af1 + 32);
    pB3 = *(const float4*)(Af1 + 36);
  } else {
    gload16(Ag0, &As[0][wbase]);
    gload16(Ag1, &As[0][wbase + 512]);
    gload16(Bg0, &Bs[0][wbase]);
    gload16(Bg1, &Bs[0][wbase + 512]);
    asm volatile("" ::: "memory");   // region boundary
    gload16(Ag0 + 32, &As[1][wbase]);
    gload16(Ag1 + 32, &As[1][wbase + 512]);
    gload16(Bg0 + 32, &Bs[1][wbase]);
    gload16(Bg1 + 32, &Bs[1][wbase + 512]);
  }

#define GEMM_STEP(BUF, TT, P0, P1, P2, P3)                                     \
  {                                                                            \
    if (AFP32) {                                                               \
      u16x8 c0, c1;                                                            \
      c0[0] = f2bf(P0.x); c0[1] = f2bf(P0.y); c0[2] = f2bf(P0.z); c0[3] = f2bf(P0.w); \
      c0[4] = f2bf(P1.x); c0[5] = f2bf(P1.y); c0[6] = f2bf(P1.z); c0[7] = f2bf(P1.w); \
      c1[0] = f2bf(P2.x); c1[1] = f2bf(P2.y); c1[2] = f2bf(P2.z); c1[3] = f2bf(P2.w); \
      c1[4] = f2bf(P3.x); c1[5] = f2bf(P3.y); c1[6] = f2bf(P3.z); c1[7] = f2bf(P3.w); \
      *(u16x8*)&As[BUF][sslot0] = c0;                                          \
      *(u16x8*)&As[BUF][sslot1] = c1;                                          \
      /* vmcnt(6): retires the tile-TT issue region (2 B-DMA + 4 A-loads);     \
         lgkmcnt(0): my ds_writes of A visible before the barrier. */          \
      asm volatile("s_waitcnt vmcnt(6) lgkmcnt(0)\n\ts_barrier" ::: "memory"); \
    } else {                                                                   \
      /* vmcnt(4): exactly one 4-op region (tile TT+1) left in flight */       \
      asm volatile("s_waitcnt vmcnt(4)\n\ts_barrier" ::: "memory");            \
    }                                                                          \
    bf16x8 af[4], bfr[4];                                                      \
    _Pragma("unroll")                                                          \
    for (int mt = 0; mt < 4; mt++)                                             \
      af[mt] = *(const bf16x8*)&As[BUF][(wm * 4 + mt) * 512 + ro];             \
    _Pragma("unroll")                                                          \
    for (int nt = 0; nt < 4; nt++)                                             \
      bfr[nt] = *(const bf16x8*)&Bs[BUF][(wn * 4 + nt) * 512 + ro];            \
    /* my fragment reads retired -> safe for anyone to overwrite buf after */  \
    asm volatile("s_waitcnt lgkmcnt(0)\n\ts_barrier" ::: "memory");            \
    const int tp = ((TT) + 2 < T) ? (TT) + 2 : T - 1;                          \
    const int kp = tp << 5;                                                    \
    if (AFP32) {                                                               \
      gload16(Bg0 + kp, &Bs[BUF][wbase]);                                      \
      gload16(Bg1 + kp, &Bs[BUF][wbase + 512]);                                \
      P0 = *(const float4*)(Af0 + kp);                                         \
      P1 = *(const float4*)(Af0 + kp + 4);                                     \
      P2 = *(const float4*)(Af1 + kp);                                         \
      P3 = *(const float4*)(Af1 + kp + 4);                                     \
    } else {                                                                   \
      gload16(Ag0 + kp, &As[BUF][wbase]);                                      \
      gload16(Ag1 + kp, &As[BUF][wbase + 512]);                                \
      gload16(Bg0 + kp, &Bs[BUF][wbase]);                                      \
      gload16(Bg1 + kp, &Bs[BUF][wbase + 512]);                                \
    }                                                                          \
    _Pragma("unroll")                                                          \
    for (int mt = 0; mt < 4; mt++)                                             \
      _Pragma("unroll")                                                        \
      for (int nt = 0; nt < 4; nt++)                                           \
        acc[mt][nt] = __builtin_amdgcn_mfma_f32_16x16x32_bf16(af[mt], bfr[nt], \
                                                              acc[mt][nt], 0, 0, 0); \
  }

  for (int t = 0; t < T; t += 2) {
    GEMM_STEP(0, t,     pA0, pA1, pA2, pA3)
    GEMM_STEP(1, t + 1, pB0, pB1, pB2, pB3)
  }
#undef GEMM_STEP

  // drain in-flight LDS-DMA (tail re-issues) before LDS dealloc / endpgm
  asm volatile("s_waitcnt vmcnt(0)" ::: "memory");

  // epilogue: C/D layout col = lane&15, row = quad*4 + reg  [m89/m91 verified]
  const int rbase = bm * 128 + wm * 64 + quad * 4;
  const int cbase = bn * 128 + wn * 64 + l15;
#pragma unroll
  for (int nt = 0; nt < 4; nt++) {
    int col = cbase + nt * 16;
    float bvad = bias ? bias[col] : 0.0f;
#pragma unroll
    for (int mt = 0; mt < 4; mt++) {
#pragma unroll
      for (int r = 0; r < 4; r++) {
        int row = rbase + mt * 16 + r;
        float v = acc[mt][nt][r] + bvad;
        if (BF16OUT) ((u16*)Cv)[(size_t)row * N + col] = f2bf(v);
        else         ((float*)Cv)[(size_t)row * N + col] = v;
      }
    }
  }
}

// ---------------- diag: 0.5*scale^2*||row||^2 over Qb/Kb rows of 512 ----------------
// grid 16384 x 256: 4 waves/block, one row per wave; rows 0..32767 -> Q, 32768.. -> K.
__global__ void diag_kernel(const u16* __restrict__ Qb, const u16* __restrict__ Kb,
                            float* __restrict__ dq, float* __restrict__ dk) {
  const int wave = threadIdx.x >> 6, lane = threadIdx.x & 63;
  int row = blockIdx.x * 4 + wave;
  const u16* src; float* dst; int r;
  if (row < HROWS) { src = Qb; dst = dq; r = row; }
  else             { src = Kb; dst = dk; r = row - HROWS; }
  const ushort4* p = (const ushort4*)(src + (size_t)r * DEPTH);
  ushort4 u0 = p[lane * 2], u1 = p[lane * 2 + 1];
  float s = 0.f, f;
  f = bf2f(u0.x); s += f * f; f = bf2f(u0.y); s += f * f;
  f = bf2f(u0.z); s += f * f; f = bf2f(u0.w); s += f * f;
  f = bf2f(u1.x); s += f * f; f = bf2f(u1.y); s += f * f;
  f = bf2f(u1.z); s += f * f; f = bf2f(u1.w); s += f * f;
#pragma unroll
  for (int o = 32; o; o >>= 1) s += __shfl_xor(s, o);
  if (lane == 0) dst[r] = s * HALF_SCALE2;
}

// ---------------- global max of k_dash per (batch,head) ----------------
// stage 1: grid 512 = 8 groups * 64 s-blocks (64 s each); one partial per block.
__global__ void maxk_part_kernel(const float* __restrict__ kd, float* __restrict__ partials) {
  int g = blockIdx.x >> 6;   // b*2+h
  int sb = blockIdx.x & 63;
  int b = g >> 1, h = g & 1;
  int tid = threadIdx.x;
  float mx = -3.4e38f;
  for (int j = 0; j < 64; j++) {
    int s = sb * 64 + j;
    int row = b * 8192 + s * 2 + h;
    mx = fmaxf(mx, kd[(size_t)row * NF + tid]);
  }
#pragma unroll
  for (int o = 32; o; o >>= 1) mx = fmaxf(mx, __shfl_xor(mx, o));
  __shared__ float wmax[4];
  if ((tid & 63) == 0) wmax[tid >> 6] = mx;
  __syncthreads();
  if (tid == 0)
    partials[blockIdx.x] = fmaxf(fmaxf(wmax[0], wmax[1]), fmaxf(wmax[2], wmax[3]));
}

// stage 2: 8 blocks x 64 lanes.
__global__ void maxk_final_kernel(const float* __restrict__ partials, float* __restrict__ mxk) {
  float v = partials[blockIdx.x * 64 + threadIdx.x];
#pragma unroll
  for (int o = 32; o; o >>= 1) v = fmaxf(v, __shfl_xor(v, o));
  if (threadIdx.x == 0) mxk[blockIdx.x] = v;
}

// ---------------- fused exp + 4x4 batch-contraction attention ----------------
// One block per (s,h). q',k' via online exp; A = q'k'^T (4x4); out = (A@v)/rowsum(A).
// Writes concat bf16 at flat s*4096 + h*2048 + batch*512 + d (the reshape quirk).
__global__ __launch_bounds__(256) void attn_kernel(
    const float* __restrict__ qd, const float* __restrict__ kd,
    const float* __restrict__ diagq, const float* __restrict__ diagk,
    const float* __restrict__ mxk, const u16* __restrict__ Vb,
    u16* __restrict__ concat) {
  int s = blockIdx.x >> 1, h = blockIdx.x & 1;
  int t = threadIdx.x;           // 256 threads; thread t <-> feature m = t
  int wave = t >> 6, lane = t & 63;
  __shared__ float qp[4][256], kp[4][256];
  __shared__ float As[4][4];
  __shared__ float wred[4][4];   // [wave][b]
  __shared__ float mqs[4];

  float qv[4], kv[4];
  int rows[4];
#pragma unroll
  for (int b = 0; b < 4; b++) {
    int r = b * 8192 + s * 2 + h;
    rows[b] = r;
    qv[b] = qd[(size_t)r * NF + t];
    kv[b] = kd[(size_t)r * NF + t];
  }
  // per-row max of q_dash (max over m == over the 256 threads)
#pragma unroll
  for (int b = 0; b < 4; b++) {
    float v = qv[b];
#pragma unroll
    for (int o = 32; o; o >>= 1) v = fmaxf(v, __shfl_xor(v, o));
    if (lane == 0) wred[wave][b] = v;
  }
  __syncthreads();
  if (t < 4) mqs[t] = fmaxf(fmaxf(wred[0][t], wred[1][t]), fmaxf(wred[2][t], wred[3][t]));
  __syncthreads();
#pragma unroll
  for (int b = 0; b < 4; b++) {
    qp[b][t] = __expf(qv[b] - diagq[rows[b]] - mqs[b]) + 1e-6f;
    kp[b][t] = __expf(kv[b] - diagk[rows[b]] - mxk[b * 2 + h]) + 1e-6f;
  }
  __syncthreads();
  // A[i][j] = sum_m qp[i][m]*kp[j][m]; wave i computes row i.
  {
    int i = wave;
    float p0 = 0, p1 = 0, p2 = 0, p3 = 0;
    for (int m = lane; m < 256; m += 64) {
      float q = qp[i][m];
      p0 += q * kp[0][m]; p1 += q * kp[1][m];
      p2 += q * kp[2][m]; p3 += q * kp[3][m];
    }
#pragma unroll
    for (int o = 32; o; o >>= 1) {
      p0 += __shfl_xor(p0, o); p1 += __shfl_xor(p1, o);
      p2 += __shfl_xor(p2, o); p3 += __shfl_xor(p3, o);
    }
    if (lane == 0) { As[i][0] = p0; As[i][1] = p1; As[i][2] = p2; As[i][3] = p3; }
  }
  __syncthreads();
  float a00 = As[0][0], a01 = As[0][1], a02 = As[0][2], a03 = As[0][3];
  float a10 = As[1][0], a11 = As[1][1], a12 = As[1][2], a13 = As[1][3];
  float a20 = As[2][0], a21 = As[2][1], a22 = As[2][2], a23 = As[2][3];
  float a30 = As[3][0], a31 = As[3][1], a32 = As[3][2], a33 = As[3][3];
  float n0 = 1.f / (a00 + a01 + a02 + a03);
  float n1 = 1.f / (a10 + a11 + a12 + a13);
  float n2 = 1.f / (a20 + a21 + a22 + a23);
  float n3 = 1.f / (a30 + a31 + a32 + a33);
  size_t obase = (size_t)s * 4096 + (size_t)h * 2048;
#pragma unroll
  for (int dp = 0; dp < 2; dp++) {
    int d = t + dp * 256;
    float v0 = bf2f(Vb[((size_t)(0 * SEQ + s)) * D_MODEL + h * DEPTH + d]);
    float v1 = bf2f(Vb[((size_t)(1 * SEQ + s)) * D_MODEL + h * DEPTH + d]);
    float v2 = bf2f(Vb[((size_t)(2 * SEQ + s)) * D_MODEL + h * DEPTH + d]);
    float v3 = bf2f(Vb[((size_t)(3 * SEQ + s)) * D_MODEL + h * DEPTH + d]);
    concat[obase + 0 * 512 + d] = f2bf((a00 * v0 + a01 * v1 + a02 * v2 + a03 * v3) * n0);
    concat[obase + 1 * 512 + d] = f2bf((a10 * v0 + a11 * v1 + a12 * v2 + a13 * v3) * n1);
    concat[obase + 2 * 512 + d] = f2bf((a20 * v0 + a21 * v1 + a22 * v2 + a23 * v3) * n2);
    concat[obase + 3 * 512 + d] = f2bf((a30 * v0 + a31 * v1 + a32 * v2 + a33 * v3) * n3);
  }
}

// ---------------- launch ----------------
extern "C" void kernel_launch(void* const* d_in, const int* in_sizes, int n_in,
                              void* d_out, int out_size, void* d_ws, size_t ws_size,
                              hipStream_t stream) {
  (void)in_sizes; (void)n_in; (void)out_size; (void)ws_size;
  const float* query = (const float*)d_in[0];
  const float* key   = (const float*)d_in[1];
  const float* value = (const float*)d_in[2];
  // d_in[3] = mask (unused by the reference computation)
  const float* Wq = (const float*)d_in[4];
  const float* bq = (const float*)d_in[5];
  const float* Wk = (const float*)d_in[6];
  const float* bk = (const float*)d_in[7];
  const float* Wv = (const float*)d_in[8];
  const float* bv = (const float*)d_in[9];
  const float* Wo = (const float*)d_in[10];
  const float* bo = (const float*)d_in[11];
  const float* proj = (const float*)d_in[12];
  float* out = (float*)d_out;

  char* w = (char*)d_ws;
  size_t o = 0;
  auto take = [&](size_t b) { void* p = w + o; o += (b + 255) & ~(size_t)255; return p; };
  u16* Wqt   = (u16*)take(2097152);
  u16* Wkt   = (u16*)take(2097152);
  u16* Wvt   = (u16*)take(2097152);
  u16* Wot   = (u16*)take(2097152);
  u16* projb = (u16*)take(262144);
  u16* Qb    = (u16*)take(33554432);    // 32768 x 512 bf16
  u16* Kb    = (u16*)take(33554432);
  u16* Vb    = (u16*)take(33554432);
  float* qd  = (float*)take(33554432);  // 32768 x 256 f32
  float* kd  = (float*)take(33554432);
  u16* concat = (u16*)take(33554432);   // 16384 x 1024 bf16
  float* diagq    = (float*)take(131072);
  float* diagk    = (float*)take(131072);
  float* partials = (float*)take(2048);
  float* mxk      = (float*)take(64);
  // peak ws use ~201 MB

  transpose4_kernel<<<dim3(32, 32, 4), dim3(32, 8), 0, stream>>>(Wq, Wk, Wv, Wo,
                                                                 Wqt, Wkt, Wvt, Wot);
  projcvt_kernel<<<128, 256, 0, stream>>>((const float4*)proj, (ushort4*)projb);

  // QKV projections fused into ONE dispatch; XCD-clustered remap inside.
  gemm_bt_kernel<true, true><<<dim3(384, 8), 256, 0, stream>>>(
      query, key, value, Wqt, Wkt, Wvt, Qb, Kb, Vb, bq, bk, bv, 1024, 1024, 128, 3);

  diag_kernel<<<16384, 256, 0, stream>>>(Qb, Kb, diagq, diagk);

  // feature projections fused into ONE dispatch (z = bm/256 selects Qb/Kb).
  gemm_bt_kernel<false, false><<<dim3(512, 2), 256, 0, stream>>>(
      Qb, Kb, nullptr, projb, projb, nullptr, qd, kd, nullptr,
      nullptr, nullptr, nullptr, 512, 256, 256, 1);

  maxk_part_kernel<<<512, 256, 0, stream>>>(kd, partials);
  maxk_final_kernel<<<8, 64, 0, stream>>>(partials, mxk);

  attn_kernel<<<8192, 256, 0, stream>>>(qd, kd, diagq, diagk, mxk, Vb, concat);

  gemm_bt_kernel<false, false><<<dim3(128, 8), 256, 0, stream>>>(
      concat, nullptr, nullptr, Wot, nullptr, nullptr, out, nullptr, nullptr,
      bo, nullptr, nullptr, 1024, 1024, 128, 3);
}

// Round 4
// 586.034 us; speedup vs baseline: 1.2099x; 1.1954x over previous
//
#include <hip/hip_runtime.h>
#include <cstdint>
#include <cstddef>

typedef unsigned short u16;
typedef __bf16 bf16x8 __attribute__((ext_vector_type(8)));
typedef unsigned short u16x8 __attribute__((ext_vector_type(8)));
typedef float   f32x4 __attribute__((ext_vector_type(4)));

#define D_MODEL 1024
#define NF      256      // num random features (M)
#define DEPTH   512
#define SEQ     4096
#define ROWS    16384    // B*L = 4*4096
#define HROWS   32768    // ROWS * NUM_HEADS (Q viewed as 32768 x 512)

// scale = 512^-0.25 ; folded into proj. 0.5*scale^2 used for diag.
#define QK_SCALE      0.21022410381342864f
#define HALF_SCALE2   0.022097086912079608f

__device__ __forceinline__ u16 f2bf(float f) {
  union { float f; uint32_t u; } x; x.f = f;
  uint32_t r = x.u + 0x7FFFu + ((x.u >> 16) & 1u);
  return (u16)(r >> 16);
}
__device__ __forceinline__ float bf2f(u16 u) {
  union { uint32_t u; float f; } x; x.u = ((uint32_t)u) << 16;
  return x.f;
}

// monotone float<->uint encoding for atomicMax on signed floats
__device__ __forceinline__ unsigned encf(float f) {
  unsigned u = __float_as_uint(f);
  return u ^ ((u >> 31) ? 0xFFFFFFFFu : 0x80000000u);
}
__device__ __forceinline__ float decf(unsigned e) {
  return (e & 0x80000000u) ? __uint_as_float(e ^ 0x80000000u)
                           : __uint_as_float(~e);
}

// async global->LDS, 16B per lane; LDS dest = wave-uniform base + lane*16B.
__device__ __forceinline__ void gload16(const u16* g, u16* l) {
  __builtin_amdgcn_global_load_lds((const __attribute__((address_space(1))) void*)g,
                                   (__attribute__((address_space(3))) void*)l,
                                   16, 0, 0);
}

// ---------------- weight prep kernels ----------------

// W (1024x1024 f32) -> W^T bf16 ([N][K] layout for gemm_bt). blockIdx.z picks matrix.
__global__ void transpose4_kernel(const float* __restrict__ w0, const float* __restrict__ w1,
                                  const float* __restrict__ w2, const float* __restrict__ w3,
                                  u16* __restrict__ o0, u16* __restrict__ o1,
                                  u16* __restrict__ o2, u16* __restrict__ o3) {
  __shared__ float tile[32][33];
  int z = blockIdx.z;
  const float* src = (z == 0) ? w0 : (z == 1) ? w1 : (z == 2) ? w2 : w3;
  u16* dst         = (z == 0) ? o0 : (z == 1) ? o1 : (z == 2) ? o2 : o3;
  int bx = blockIdx.x * 32, by = blockIdx.y * 32;
  int tx = threadIdx.x, ty = threadIdx.y;  // block (32,8)
#pragma unroll
  for (int r = ty; r < 32; r += 8) tile[r][tx] = src[(size_t)(by + r) * D_MODEL + bx + tx];
  __syncthreads();
#pragma unroll
  for (int r = ty; r < 32; r += 8)
    dst[(size_t)(bx + r) * D_MODEL + by + tx] = f2bf(tile[tx][r]);
}

// proj (256x512 f32) -> bf16 with qk scale folded in. 32768 threads, 4 elems each.
__global__ void projcvt_kernel(const float4* __restrict__ p, ushort4* __restrict__ o) {
  int i = blockIdx.x * 256 + threadIdx.x;
  float4 a = p[i];
  o[i] = make_ushort4(f2bf(a.x * QK_SCALE), f2bf(a.y * QK_SCALE),
                      f2bf(a.z * QK_SCALE), f2bf(a.w * QK_SCALE));
}

// ---------------- GEMM: C[M][N] = A[M][K] @ B[N][K]^T + bias ----------------
// Round-0 proven structure (593.8 us session-best): 128x128 tile, BK=32,
// 256 threads = 4 waves in 2x2 grid, each wave 64x64 via 4x4
// mfma_f32_16x16x32_bf16. Double-buffered LDS, prefetch-ahead, __syncthreads.
// (Rounds 2-3 falsified the counted-vmcnt rewrite: FETCH and BW moved 3-5x
// with zero effect on duration -> structure-bound; reverted verbatim.)
//
// LDS chunk swizzle: tile row stride is 64 B, so identity placement makes
// b128 reads 8-way bank-conflicted. Lane l stages global chunk
// c = ((l&3)-(l>>3))&3 of row l>>2 into dense slot l (DMA-compatible);
// reads use slot (quad + (l15>>1))&3 -> exactly 2 lanes/bank-group (free).
//
// MODE (new, feature GEMMs only):
//  1: accumulate diag = 0.5*scale^2*||A-row||^2 from af fragments (af[mt] is
//     exactly row (wm*4+mt)*16+l15, cols quad*8..+8 per K-step — the same
//     mapping that feeds the MFMA, so it is verified by GEMM correctness).
//     Quad-reduce via shfl_xor(16,32); writer: wn==0 && quad==0; bn==0 only.
//  2: MODE1 + per-(batch,head) global max of C via monotone-uint atomicMax
//     (row parity r&1 = head, bm>>6 = batch). Buffer memset to 0 (= -inf
//     encoding) every launch -> graph-replay idempotent.
template <bool BF16OUT, bool AFP32, int MODE>
__global__ __launch_bounds__(256) void gemm_bt_kernel(
    const void* __restrict__ Av, const u16* __restrict__ B, void* __restrict__ Cv,
    const float* __restrict__ bias, int K, int N,
    float* __restrict__ diagOut, unsigned* __restrict__ maxEnc) {
  __shared__ __align__(16) u16 As[2][128 * 32];
  __shared__ __align__(16) u16 Bs[2][128 * 32];
  const int tid  = threadIdx.x;
  const int lane = tid & 63;
  const int wave = tid >> 6;
  const int wm = wave >> 1, wn = wave & 1;
  const int quad = lane >> 4, l15 = lane & 15;
  const int bm = blockIdx.x, bn = blockIdx.y;   // bm fast -> XCD locality

  const int srow   = lane >> 2;
  const int schunk = ((lane & 3) - (lane >> 3)) & 3;   // swizzled chunk for lane
  const int scol   = schunk * 8;

  const u16* Bb  = B + (size_t)bn * 128 * K;
  const u16* Bg0 = Bb + (size_t)(wave * 32 + srow) * K + scol;
  const u16* Bg1 = Bg0 + (size_t)16 * K;

  const float* Af0 = nullptr; const float* Af1 = nullptr;
  const u16*   Ag0 = nullptr; const u16*   Ag1 = nullptr;
  if (AFP32) {
    const float* Ab = (const float*)Av + (size_t)bm * 128 * K;
    Af0 = Ab + (size_t)(wave * 32 + srow) * K + scol;
    Af1 = Af0 + (size_t)16 * K;
  } else {
    const u16* Ab = (const u16*)Av + (size_t)bm * 128 * K;
    Ag0 = Ab + (size_t)(wave * 32 + srow) * K + scol;
    Ag1 = Ag0 + (size_t)16 * K;
  }

  const int sslot0 = wave * 1024 + lane * 8;   // dense lane slot (u16 units)
  const int sslot1 = sslot0 + 512;
  // swizzled read offset within a 16-row group (u16 units)
  const int ro = l15 * 32 + (((quad + (l15 >> 1)) & 3) * 8);

  f32x4 acc[4][4] = {};
  float dsum[4] = {0.f, 0.f, 0.f, 0.f};
  float4 p00, p01, p10, p11;

  // ---- prologue: tile 0 ----
  if (AFP32) {
    p00 = *(const float4*)(Af0);
    p01 = *(const float4*)(Af0 + 4);
    p10 = *(const float4*)(Af1);
    p11 = *(const float4*)(Af1 + 4);
  } else {
    gload16(Ag0, &As[0][wave * 1024]);
    gload16(Ag1, &As[0][wave * 1024 + 512]);
  }
  gload16(Bg0, &Bs[0][wave * 1024]);
  gload16(Bg1, &Bs[0][wave * 1024 + 512]);

  for (int k0 = 0; k0 < K; k0 += 32) {
    const int buf = (k0 >> 5) & 1;
    const int nxt = buf ^ 1;
    __syncthreads();   // tile(k) DMA/regs complete; readers of buf (iter k-2) done
    if (AFP32) {
      u16x8 c0, c1;
      c0[0]=f2bf(p00.x); c0[1]=f2bf(p00.y); c0[2]=f2bf(p00.z); c0[3]=f2bf(p00.w);
      c0[4]=f2bf(p01.x); c0[5]=f2bf(p01.y); c0[6]=f2bf(p01.z); c0[7]=f2bf(p01.w);
      c1[0]=f2bf(p10.x); c1[1]=f2bf(p10.y); c1[2]=f2bf(p10.z); c1[3]=f2bf(p10.w);
      c1[4]=f2bf(p11.x); c1[5]=f2bf(p11.y); c1[6]=f2bf(p11.z); c1[7]=f2bf(p11.w);
      *(u16x8*)&As[buf][sslot0] = c0;
      *(u16x8*)&As[buf][sslot1] = c1;
      __syncthreads();   // A tile visible (vmcnt already 0: nothing else in flight)
      if (k0 + 32 < K) {
        p00 = *(const float4*)(Af0 + k0 + 32);
        p01 = *(const float4*)(Af0 + k0 + 36);
        p10 = *(const float4*)(Af1 + k0 + 32);
        p11 = *(const float4*)(Af1 + k0 + 36);
        gload16(Bg0 + k0 + 32, &Bs[nxt][wave * 1024]);
        gload16(Bg1 + k0 + 32, &Bs[nxt][wave * 1024 + 512]);
      }
    } else {
      if (k0 + 32 < K) {
        gload16(Ag0 + k0 + 32, &As[nxt][wave * 1024]);
        gload16(Ag1 + k0 + 32, &As[nxt][wave * 1024 + 512]);
        gload16(Bg0 + k0 + 32, &Bs[nxt][wave * 1024]);
        gload16(Bg1 + k0 + 32, &Bs[nxt][wave * 1024 + 512]);
      }
    }
    // ---- compute tile k from buf (swizzled reads, 2-way conflict = free) ----
    bf16x8 af[4], bfr[4];
#pragma unroll
    for (int mt = 0; mt < 4; mt++)
      af[mt] = *(const bf16x8*)&As[buf][(wm * 4 + mt) * 512 + ro];
#pragma unroll
    for (int nt = 0; nt < 4; nt++)
      bfr[nt] = *(const bf16x8*)&Bs[buf][(wn * 4 + nt) * 512 + ro];
    if (MODE >= 1) {
#pragma unroll
      for (int mt = 0; mt < 4; mt++) {
#pragma unroll
        for (int j = 0; j < 8; j++) { float v = (float)af[mt][j]; dsum[mt] += v * v; }
      }
    }
#pragma unroll
    for (int mt = 0; mt < 4; mt++)
#pragma unroll
      for (int nt = 0; nt < 4; nt++)
        acc[mt][nt] = __builtin_amdgcn_mfma_f32_16x16x32_bf16(af[mt], bfr[nt], acc[mt][nt], 0, 0, 0);
  }

  // ---- diag write (MODE>=1): reduce the 4 k-chunk quads, single writer ----
  if (MODE >= 1) {
#pragma unroll
    for (int mt = 0; mt < 4; mt++) {
      float s = dsum[mt];
      s += __shfl_xor(s, 16);
      s += __shfl_xor(s, 32);
      if (bn == 0 && wn == 0 && quad == 0)
        diagOut[bm * 128 + (wm * 4 + mt) * 16 + l15] = s * HALF_SCALE2;
    }
  }

  // ---- per-(batch,head) max of C (MODE==2) ----
  if (MODE == 2) {
    float me0 = -3.4e38f, me1 = -3.4e38f;   // head = row parity = r&1
#pragma unroll
    for (int mt = 0; mt < 4; mt++)
#pragma unroll
      for (int nt = 0; nt < 4; nt++) {
        me0 = fmaxf(me0, fmaxf(acc[mt][nt][0], acc[mt][nt][2]));
        me1 = fmaxf(me1, fmaxf(acc[mt][nt][1], acc[mt][nt][3]));
      }
#pragma unroll
    for (int o = 32; o; o >>= 1) {
      me0 = fmaxf(me0, __shfl_xor(me0, o));
      me1 = fmaxf(me1, __shfl_xor(me1, o));
    }
    __syncthreads();                       // LDS tiles dead; reuse as scratch
    float* sc = (float*)&As[0][0];
    if (lane == 0) { sc[wave * 2] = me0; sc[wave * 2 + 1] = me1; }
    __syncthreads();
    if (tid == 0) {
      float m0 = fmaxf(fmaxf(sc[0], sc[2]), fmaxf(sc[4], sc[6]));
      float m1 = fmaxf(fmaxf(sc[1], sc[3]), fmaxf(sc[5], sc[7]));
      int b = bm >> 6;                     // 64 blocks of 128 rows per batch
      atomicMax(&maxEnc[b * 2 + 0], encf(m0));
      atomicMax(&maxEnc[b * 2 + 1], encf(m1));
    }
  }

  // epilogue: C/D layout col = lane&15, row = quad*4 + reg  [m89/m91 verified]
  const int rbase = bm * 128 + wm * 64 + quad * 4;
  const int cbase = bn * 128 + wn * 64 + l15;
#pragma unroll
  for (int nt = 0; nt < 4; nt++) {
    int col = cbase + nt * 16;
    float bvad = bias ? bias[col] : 0.0f;
#pragma unroll
    for (int mt = 0; mt < 4; mt++) {
#pragma unroll
      for (int r = 0; r < 4; r++) {
        int row = rbase + mt * 16 + r;
        float v = acc[mt][nt][r] + bvad;
        if (BF16OUT) ((u16*)Cv)[(size_t)row * N + col] = f2bf(v);
        else         ((float*)Cv)[(size_t)row * N + col] = v;
      }
    }
  }
}

// ---------------- fused exp + 4x4 batch-contraction attention ----------------
// One block per (s,h). q',k' via online exp; A = q'k'^T (4x4); out = (A@v)/rowsum(A).
// Writes concat bf16 at flat s*4096 + h*2048 + batch*512 + d (the reshape quirk).
__global__ __launch_bounds__(256) void attn_kernel(
    const float* __restrict__ qd, const float* __restrict__ kd,
    const float* __restrict__ diagq, const float* __restrict__ diagk,
    const unsigned* __restrict__ mxkE, const u16* __restrict__ Vb,
    u16* __restrict__ concat) {
  int s = blockIdx.x >> 1, h = blockIdx.x & 1;
  int t = threadIdx.x;           // 256 threads; thread t <-> feature m = t
  int wave = t >> 6, lane = t & 63;
  __shared__ float qp[4][256], kp[4][256];
  __shared__ float As[4][4];
  __shared__ float wred[4][4];   // [wave][b]
  __shared__ float mqs[4];

  float qv[4], kv[4];
  int rows[4];
#pragma unroll
  for (int b = 0; b < 4; b++) {
    int r = b * 8192 + s * 2 + h;
    rows[b] = r;
    qv[b] = qd[(size_t)r * NF + t];
    kv[b] = kd[(size_t)r * NF + t];
  }
  // per-row max of q_dash (max over m == over the 256 threads)
#pragma unroll
  for (int b = 0; b < 4; b++) {
    float v = qv[b];
#pragma unroll
    for (int o = 32; o; o >>= 1) v = fmaxf(v, __shfl_xor(v, o));
    if (lane == 0) wred[wave][b] = v;
  }
  __syncthreads();
  if (t < 4) mqs[t] = fmaxf(fmaxf(wred[0][t], wred[1][t]), fmaxf(wred[2][t], wred[3][t]));
  __syncthreads();
#pragma unroll
  for (int b = 0; b < 4; b++) {
    qp[b][t] = __expf(qv[b] - diagq[rows[b]] - mqs[b]) + 1e-6f;
    kp[b][t] = __expf(kv[b] - diagk[rows[b]] - decf(mxkE[b * 2 + h])) + 1e-6f;
  }
  __syncthreads();
  // A[i][j] = sum_m qp[i][m]*kp[j][m]; wave i computes row i.
  {
    int i = wave;
    float p0 = 0, p1 = 0, p2 = 0, p3 = 0;
    for (int m = lane; m < 256; m += 64) {
      float q = qp[i][m];
      p0 += q * kp[0][m]; p1 += q * kp[1][m];
      p2 += q * kp[2][m]; p3 += q * kp[3][m];
    }
#pragma unroll
    for (int o = 32; o; o >>= 1) {
      p0 += __shfl_xor(p0, o); p1 += __shfl_xor(p1, o);
      p2 += __shfl_xor(p2, o); p3 += __shfl_xor(p3, o);
    }
    if (lane == 0) { As[i][0] = p0; As[i][1] = p1; As[i][2] = p2; As[i][3] = p3; }
  }
  __syncthreads();
  float a00 = As[0][0], a01 = As[0][1], a02 = As[0][2], a03 = As[0][3];
  float a10 = As[1][0], a11 = As[1][1], a12 = As[1][2], a13 = As[1][3];
  float a20 = As[2][0], a21 = As[2][1], a22 = As[2][2], a23 = As[2][3];
  float a30 = As[3][0], a31 = As[3][1], a32 = As[3][2], a33 = As[3][3];
  float n0 = 1.f / (a00 + a01 + a02 + a03);
  float n1 = 1.f / (a10 + a11 + a12 + a13);
  float n2 = 1.f / (a20 + a21 + a22 + a23);
  float n3 = 1.f / (a30 + a31 + a32 + a33);
  size_t obase = (size_t)s * 4096 + (size_t)h * 2048;
#pragma unroll
  for (int dp = 0; dp < 2; dp++) {
    int d = t + dp * 256;
    float v0 = bf2f(Vb[((size_t)(0 * SEQ + s)) * D_MODEL + h * DEPTH + d]);
    float v1 = bf2f(Vb[((size_t)(1 * SEQ + s)) * D_MODEL + h * DEPTH + d]);
    float v2 = bf2f(Vb[((size_t)(2 * SEQ + s)) * D_MODEL + h * DEPTH + d]);
    float v3 = bf2f(Vb[((size_t)(3 * SEQ + s)) * D_MODEL + h * DEPTH + d]);
    concat[obase + 0 * 512 + d] = f2bf((a00 * v0 + a01 * v1 + a02 * v2 + a03 * v3) * n0);
    concat[obase + 1 * 512 + d] = f2bf((a10 * v0 + a11 * v1 + a12 * v2 + a13 * v3) * n1);
    concat[obase + 2 * 512 + d] = f2bf((a20 * v0 + a21 * v1 + a22 * v2 + a23 * v3) * n2);
    concat[obase + 3 * 512 + d] = f2bf((a30 * v0 + a31 * v1 + a32 * v2 + a33 * v3) * n3);
  }
}

// ---------------- launch ----------------
extern "C" void kernel_launch(void* const* d_in, const int* in_sizes, int n_in,
                              void* d_out, int out_size, void* d_ws, size_t ws_size,
                              hipStream_t stream) {
  (void)in_sizes; (void)n_in; (void)out_size; (void)ws_size;
  const float* query = (const float*)d_in[0];
  const float* key   = (const float*)d_in[1];
  const float* value = (const float*)d_in[2];
  // d_in[3] = mask (unused by the reference computation)
  const float* Wq = (const float*)d_in[4];
  const float* bq = (const float*)d_in[5];
  const float* Wk = (const float*)d_in[6];
  const float* bk = (const float*)d_in[7];
  const float* Wv = (const float*)d_in[8];
  const float* bv = (const float*)d_in[9];
  const float* Wo = (const float*)d_in[10];
  const float* bo = (const float*)d_in[11];
  const float* proj = (const float*)d_in[12];
  float* out = (float*)d_out;

  char* w = (char*)d_ws;
  size_t o = 0;
  auto take = [&](size_t b) { void* p = w + o; o += (b + 255) & ~(size_t)255; return p; };
  u16* Wqt   = (u16*)take(2097152);
  u16* Wkt   = (u16*)take(2097152);
  u16* Wvt   = (u16*)take(2097152);
  u16* Wot   = (u16*)take(2097152);
  u16* projb = (u16*)take(262144);
  u16* Qb    = (u16*)take(33554432);    // 32768 x 512 bf16
  u16* Kb    = (u16*)take(33554432);
  u16* Vb    = (u16*)take(33554432);
  float* qd  = (float*)take(33554432);  // 32768 x 256 f32
  float* kd  = (float*)take(33554432);
  u16* concat = (u16*)take(33554432);   // 16384 x 1024 bf16
  float* diagq    = (float*)take(131072);
  float* diagk    = (float*)take(131072);
  unsigned* mxkE  = (unsigned*)take(64);
  // peak ws use ~201 MB

  hipMemsetAsync(mxkE, 0, 64, stream);   // enc(-inf) = 0; replay-idempotent

  transpose4_kernel<<<dim3(32, 32, 4), dim3(32, 8), 0, stream>>>(Wq, Wk, Wv, Wo,
                                                                 Wqt, Wkt, Wvt, Wot);
  projcvt_kernel<<<128, 256, 0, stream>>>((const float4*)proj, (ushort4*)projb);

  // QKV projections: fp32 A fused conversion, bm on x for XCD L2 locality.
  gemm_bt_kernel<true, true, 0><<<dim3(128, 8), 256, 0, stream>>>(
      query, Wqt, Qb, bq, 1024, 1024, nullptr, nullptr);
  gemm_bt_kernel<true, true, 0><<<dim3(128, 8), 256, 0, stream>>>(
      key,   Wkt, Kb, bk, 1024, 1024, nullptr, nullptr);
  gemm_bt_kernel<true, true, 0><<<dim3(128, 8), 256, 0, stream>>>(
      value, Wvt, Vb, bv, 1024, 1024, nullptr, nullptr);

  // feature projections; diag fused (MODE1/2), k-max fused (MODE2).
  gemm_bt_kernel<false, false, 1><<<dim3(256, 2), 256, 0, stream>>>(
      Qb, projb, qd, nullptr, 512, 256, diagq, nullptr);
  gemm_bt_kernel<false, false, 2><<<dim3(256, 2), 256, 0, stream>>>(
      Kb, projb, kd, nullptr, 512, 256, diagk, mxkE);

  attn_kernel<<<8192, 256, 0, stream>>>(qd, kd, diagq, diagk, mxkE, Vb, concat);

  gemm_bt_kernel<false, false, 0><<<dim3(128, 8), 256, 0, stream>>>(
      concat, Wot, out, bo, 1024, 1024, nullptr, nullptr);
}

// Round 5
// 544.858 us; speedup vs baseline: 1.3013x; 1.0756x over previous
//
#include <hip/hip_runtime.h>
#include <cstdint>
#include <cstddef>

typedef unsigned short u16;
typedef __bf16 bf16x8 __attribute__((ext_vector_type(8)));
typedef unsigned short u16x8 __attribute__((ext_vector_type(8)));
typedef float   f32x4 __attribute__((ext_vector_type(4)));

#define D_MODEL 1024
#define NF      256      // num random features (M)
#define DEPTH   512
#define SEQ     4096
#define ROWS    16384    // B*L = 4*4096
#define HROWS   32768    // ROWS * NUM_HEADS (Q viewed as 32768 x 512)

// scale = 512^-0.25 ; folded into proj. 0.5*scale^2 used for diag.
#define QK_SCALE      0.21022410381342864f
#define HALF_SCALE2   0.022097086912079608f

__device__ __forceinline__ u16 f2bf(float f) {
  union { float f; uint32_t u; } x; x.f = f;
  uint32_t r = x.u + 0x7FFFu + ((x.u >> 16) & 1u);
  return (u16)(r >> 16);
}
__device__ __forceinline__ float bf2f(u16 u) {
  union { uint32_t u; float f; } x; x.u = ((uint32_t)u) << 16;
  return x.f;
}

// monotone float<->uint encoding for atomicMax on signed floats
__device__ __forceinline__ unsigned encf(float f) {
  unsigned u = __float_as_uint(f);
  return u ^ ((u >> 31) ? 0xFFFFFFFFu : 0x80000000u);
}
__device__ __forceinline__ float decf(unsigned e) {
  return (e & 0x80000000u) ? __uint_as_float(e ^ 0x80000000u)
                           : __uint_as_float(~e);
}

// async global->LDS, 16B per lane; LDS dest = wave-uniform base + lane*16B.
__device__ __forceinline__ void gload16(const u16* g, u16* l) {
  __builtin_amdgcn_global_load_lds((const __attribute__((address_space(1))) void*)g,
                                   (__attribute__((address_space(3))) void*)l,
                                   16, 0, 0);
}

// ---------------- weight prep kernels ----------------

// W (1024x1024 f32) -> W^T bf16 ([N][K] layout for gemm_bt). blockIdx.z picks matrix.
__global__ void transpose4_kernel(const float* __restrict__ w0, const float* __restrict__ w1,
                                  const float* __restrict__ w2, const float* __restrict__ w3,
                                  u16* __restrict__ o0, u16* __restrict__ o1,
                                  u16* __restrict__ o2, u16* __restrict__ o3) {
  __shared__ float tile[32][33];
  int z = blockIdx.z;
  const float* src = (z == 0) ? w0 : (z == 1) ? w1 : (z == 2) ? w2 : w3;
  u16* dst         = (z == 0) ? o0 : (z == 1) ? o1 : (z == 2) ? o2 : o3;
  int bx = blockIdx.x * 32, by = blockIdx.y * 32;
  int tx = threadIdx.x, ty = threadIdx.y;  // block (32,8)
#pragma unroll
  for (int r = ty; r < 32; r += 8) tile[r][tx] = src[(size_t)(by + r) * D_MODEL + bx + tx];
  __syncthreads();
#pragma unroll
  for (int r = ty; r < 32; r += 8)
    dst[(size_t)(bx + r) * D_MODEL + by + tx] = f2bf(tile[tx][r]);
}

// proj (256x512 f32) -> bf16 with qk scale folded in. 32768 threads, 4 elems each.
__global__ void projcvt_kernel(const float4* __restrict__ p, ushort4* __restrict__ o) {
  int i = blockIdx.x * 256 + threadIdx.x;
  float4 a = p[i];
  o[i] = make_ushort4(f2bf(a.x * QK_SCALE), f2bf(a.y * QK_SCALE),
                      f2bf(a.z * QK_SCALE), f2bf(a.w * QK_SCALE));
}

// ---------------- GEMM: C[M][N] = A[M][K] @ B[N][K]^T + bias ----------------
// Round-0 proven DATAFLOW (128x128 tile, BK=32, double-buffered LDS,
// __syncthreads schedule) re-tiled to 512 threads = 8 waves in a 2Mx4N grid;
// each wave computes 64x32 via 4x2 mfma_f32_16x16x32_bf16.
// Rationale (round-4 counters): the structure is latency-bound with
// OccupancyPercent ~23% (= ~2 blocks of 4 waves resident/CU). Doubling
// waves/block at the SAME 32KB LDS doubles resident waves -> more overlap
// across the per-iter vmcnt(0) drain. Per-wave staging drops to one
// gload16 of A + one of B per iter (one 16-row group each); the per-16-row
// -group swizzle/read math is carried over verbatim from the proven kernel.
//
// LDS chunk swizzle (per 16-row group, unchanged): lane l stages global
// chunk ((l&3)-(l>>3))&3 of row l>>2 into dense slot l; reads use chunk
// (quad + (l15>>1))&3 -> the swizzle cancels to A[l15][quad*8..+8] while
// making the b128 reads 2-way-conflict-free.
//
// MODE (feature GEMMs only):
//  1: diag = 0.5*scale^2*||A-row||^2 from af fragments (af[mt] is row
//     (wm*4+mt)*16+l15 cols quad*8..+8 -- mapping verified by GEMM
//     correctness). Quad-reduce shfl_xor(16,32); writer wn==0&&quad==0, bn==0.
//  2: MODE1 + per-(batch,head) max of C via monotone-uint atomicMax
//     (head = row parity r&1, batch = bm>>6). maxEnc memset to 0 (=enc(-inf))
//     every launch -> graph-replay idempotent.
template <bool BF16OUT, bool AFP32, int MODE>
__global__ __launch_bounds__(512) void gemm_bt_kernel(
    const void* __restrict__ Av, const u16* __restrict__ B, void* __restrict__ Cv,
    const float* __restrict__ bias, int K, int N,
    float* __restrict__ diagOut, unsigned* __restrict__ maxEnc) {
  __shared__ __align__(16) u16 As[2][128 * 32];
  __shared__ __align__(16) u16 Bs[2][128 * 32];
  const int tid  = threadIdx.x;
  const int lane = tid & 63;
  const int wave = tid >> 6;         // 0..7
  const int wm = wave >> 2, wn = wave & 3;   // 2M x 4N wave grid
  const int quad = lane >> 4, l15 = lane & 15;
  const int bm = blockIdx.x, bn = blockIdx.y;   // bm fast -> XCD locality

  const int srow   = lane >> 2;                        // 0..15 within group
  const int schunk = ((lane & 3) - (lane >> 3)) & 3;   // swizzled chunk for lane
  const int scol   = schunk * 8;

  // each wave stages one 16-row group (group index == wave)
  const u16* Bg = B + (size_t)bn * 128 * K + (size_t)(wave * 16 + srow) * K + scol;

  const float* Af = nullptr;
  const u16*   Ag = nullptr;
  if (AFP32) {
    Af = (const float*)Av + (size_t)bm * 128 * K + (size_t)(wave * 16 + srow) * K + scol;
  } else {
    Ag = (const u16*)Av + (size_t)bm * 128 * K + (size_t)(wave * 16 + srow) * K + scol;
  }

  const int ws    = wave * 512;        // wave's 16-row group in LDS (u16 units)
  const int sslot = ws + lane * 8;     // dense lane slot
  // swizzled read offset within a 16-row group (u16 units)
  const int ro = l15 * 32 + (((quad + (l15 >> 1)) & 3) * 8);

  f32x4 acc[4][2] = {};
  float dsum[4] = {0.f, 0.f, 0.f, 0.f};
  float4 p00, p01;

  // ---- prologue: tile 0 ----
  if (AFP32) {
    p00 = *(const float4*)(Af);
    p01 = *(const float4*)(Af + 4);
  } else {
    gload16(Ag, &As[0][ws]);
  }
  gload16(Bg, &Bs[0][ws]);

  for (int k0 = 0; k0 < K; k0 += 32) {
    const int buf = (k0 >> 5) & 1;
    const int nxt = buf ^ 1;
    __syncthreads();   // tile(k) DMA complete; readers of buf (iter k-2) done
    if (AFP32) {
      u16x8 c0;
      c0[0]=f2bf(p00.x); c0[1]=f2bf(p00.y); c0[2]=f2bf(p00.z); c0[3]=f2bf(p00.w);
      c0[4]=f2bf(p01.x); c0[5]=f2bf(p01.y); c0[6]=f2bf(p01.z); c0[7]=f2bf(p01.w);
      *(u16x8*)&As[buf][sslot] = c0;
      __syncthreads();   // A tile visible (vmcnt already 0: nothing else in flight)
      if (k0 + 32 < K) {
        p00 = *(const float4*)(Af + k0 + 32);
        p01 = *(const float4*)(Af + k0 + 36);
        gload16(Bg + k0 + 32, &Bs[nxt][ws]);
      }
    } else {
      if (k0 + 32 < K) {
        gload16(Ag + k0 + 32, &As[nxt][ws]);
        gload16(Bg + k0 + 32, &Bs[nxt][ws]);
      }
    }
    // ---- compute tile k from buf (swizzled reads, 2-way conflict = free) ----
    bf16x8 af[4], bfr[2];
#pragma unroll
    for (int mt = 0; mt < 4; mt++)
      af[mt] = *(const bf16x8*)&As[buf][(wm * 4 + mt) * 512 + ro];
#pragma unroll
    for (int nt = 0; nt < 2; nt++)
      bfr[nt] = *(const bf16x8*)&Bs[buf][(wn * 2 + nt) * 512 + ro];
    if (MODE >= 1) {
#pragma unroll
      for (int mt = 0; mt < 4; mt++) {
#pragma unroll
        for (int j = 0; j < 8; j++) { float v = (float)af[mt][j]; dsum[mt] += v * v; }
      }
    }
#pragma unroll
    for (int mt = 0; mt < 4; mt++)
#pragma unroll
      for (int nt = 0; nt < 2; nt++)
        acc[mt][nt] = __builtin_amdgcn_mfma_f32_16x16x32_bf16(af[mt], bfr[nt], acc[mt][nt], 0, 0, 0);
  }

  // ---- diag write (MODE>=1): reduce the 4 k-chunk quads, single writer ----
  if (MODE >= 1) {
#pragma unroll
    for (int mt = 0; mt < 4; mt++) {
      float s = dsum[mt];
      s += __shfl_xor(s, 16);
      s += __shfl_xor(s, 32);
      if (bn == 0 && wn == 0 && quad == 0)
        diagOut[bm * 128 + (wm * 4 + mt) * 16 + l15] = s * HALF_SCALE2;
    }
  }

  // ---- per-(batch,head) max of C (MODE==2) ----
  if (MODE == 2) {
    float me0 = -3.4e38f, me1 = -3.4e38f;   // head = row parity = r&1
#pragma unroll
    for (int mt = 0; mt < 4; mt++)
#pragma unroll
      for (int nt = 0; nt < 2; nt++) {
        me0 = fmaxf(me0, fmaxf(acc[mt][nt][0], acc[mt][nt][2]));
        me1 = fmaxf(me1, fmaxf(acc[mt][nt][1], acc[mt][nt][3]));
      }
#pragma unroll
    for (int o = 32; o; o >>= 1) {
      me0 = fmaxf(me0, __shfl_xor(me0, o));
      me1 = fmaxf(me1, __shfl_xor(me1, o));
    }
    __syncthreads();                       // LDS tiles dead; reuse as scratch
    float* sc = (float*)&As[0][0];
    if (lane == 0) { sc[wave * 2] = me0; sc[wave * 2 + 1] = me1; }
    __syncthreads();
    if (tid == 0) {
      float m0 = sc[0], m1 = sc[1];
#pragma unroll
      for (int wv = 1; wv < 8; wv++) {
        m0 = fmaxf(m0, sc[wv * 2]);
        m1 = fmaxf(m1, sc[wv * 2 + 1]);
      }
      int b = bm >> 6;                     // 64 blocks of 128 rows per batch
      atomicMax(&maxEnc[b * 2 + 0], encf(m0));
      atomicMax(&maxEnc[b * 2 + 1], encf(m1));
    }
  }

  // epilogue: C/D layout col = lane&15, row = quad*4 + reg  [m89/m91 verified]
  const int rbase = bm * 128 + wm * 64 + quad * 4;
  const int cbase = bn * 128 + wn * 32 + l15;
#pragma unroll
  for (int nt = 0; nt < 2; nt++) {
    int col = cbase + nt * 16;
    float bvad = bias ? bias[col] : 0.0f;
#pragma unroll
    for (int mt = 0; mt < 4; mt++) {
#pragma unroll
      for (int r = 0; r < 4; r++) {
        int row = rbase + mt * 16 + r;
        float v = acc[mt][nt][r] + bvad;
        if (BF16OUT) ((u16*)Cv)[(size_t)row * N + col] = f2bf(v);
        else         ((float*)Cv)[(size_t)row * N + col] = v;
      }
    }
  }
}

// ---------------- fused exp + 4x4 batch-contraction attention ----------------
// One block per (s,h). q',k' via online exp; A = q'k'^T (4x4); out = (A@v)/rowsum(A).
// Writes concat bf16 at flat s*4096 + h*2048 + batch*512 + d (the reshape quirk).
__global__ __launch_bounds__(256) void attn_kernel(
    const float* __restrict__ qd, const float* __restrict__ kd,
    const float* __restrict__ diagq, const float* __restrict__ diagk,
    const unsigned* __restrict__ mxkE, const u16* __restrict__ Vb,
    u16* __restrict__ concat) {
  int s = blockIdx.x >> 1, h = blockIdx.x & 1;
  int t = threadIdx.x;           // 256 threads; thread t <-> feature m = t
  int wave = t >> 6, lane = t & 63;
  __shared__ float qp[4][256], kp[4][256];
  __shared__ float As[4][4];
  __shared__ float wred[4][4];   // [wave][b]
  __shared__ float mqs[4];

  float qv[4], kv[4];
  int rows[4];
#pragma unroll
  for (int b = 0; b < 4; b++) {
    int r = b * 8192 + s * 2 + h;
    rows[b] = r;
    qv[b] = qd[(size_t)r * NF + t];
    kv[b] = kd[(size_t)r * NF + t];
  }
  // per-row max of q_dash (max over m == over the 256 threads)
#pragma unroll
  for (int b = 0; b < 4; b++) {
    float v = qv[b];
#pragma unroll
    for (int o = 32; o; o >>= 1) v = fmaxf(v, __shfl_xor(v, o));
    if (lane == 0) wred[wave][b] = v;
  }
  __syncthreads();
  if (t < 4) mqs[t] = fmaxf(fmaxf(wred[0][t], wred[1][t]), fmaxf(wred[2][t], wred[3][t]));
  __syncthreads();
#pragma unroll
  for (int b = 0; b < 4; b++) {
    qp[b][t] = __expf(qv[b] - diagq[rows[b]] - mqs[b]) + 1e-6f;
    kp[b][t] = __expf(kv[b] - diagk[rows[b]] - decf(mxkE[b * 2 + h])) + 1e-6f;
  }
  __syncthreads();
  // A[i][j] = sum_m qp[i][m]*kp[j][m]; wave i computes row i.
  {
    int i = wave;
    float p0 = 0, p1 = 0, p2 = 0, p3 = 0;
    for (int m = lane; m < 256; m += 64) {
      float q = qp[i][m];
      p0 += q * kp[0][m]; p1 += q * kp[1][m];
      p2 += q * kp[2][m]; p3 += q * kp[3][m];
    }
#pragma unroll
    for (int o = 32; o; o >>= 1) {
      p0 += __shfl_xor(p0, o); p1 += __shfl_xor(p1, o);
      p2 += __shfl_xor(p2, o); p3 += __shfl_xor(p3, o);
    }
    if (lane == 0) { As[i][0] = p0; As[i][1] = p1; As[i][2] = p2; As[i][3] = p3; }
  }
  __syncthreads();
  float a00 = As[0][0], a01 = As[0][1], a02 = As[0][2], a03 = As[0][3];
  float a10 = As[1][0], a11 = As[1][1], a12 = As[1][2], a13 = As[1][3];
  float a20 = As[2][0], a21 = As[2][1], a22 = As[2][2], a23 = As[2][3];
  float a30 = As[3][0], a31 = As[3][1], a32 = As[3][2], a33 = As[3][3];
  float n0 = 1.f / (a00 + a01 + a02 + a03);
  float n1 = 1.f / (a10 + a11 + a12 + a13);
  float n2 = 1.f / (a20 + a21 + a22 + a23);
  float n3 = 1.f / (a30 + a31 + a32 + a33);
  size_t obase = (size_t)s * 4096 + (size_t)h * 2048;
#pragma unroll
  for (int dp = 0; dp < 2; dp++) {
    int d = t + dp * 256;
    float v0 = bf2f(Vb[((size_t)(0 * SEQ + s)) * D_MODEL + h * DEPTH + d]);
    float v1 = bf2f(Vb[((size_t)(1 * SEQ + s)) * D_MODEL + h * DEPTH + d]);
    float v2 = bf2f(Vb[((size_t)(2 * SEQ + s)) * D_MODEL + h * DEPTH + d]);
    float v3 = bf2f(Vb[((size_t)(3 * SEQ + s)) * D_MODEL + h * DEPTH + d]);
    concat[obase + 0 * 512 + d] = f2bf((a00 * v0 + a01 * v1 + a02 * v2 + a03 * v3) * n0);
    concat[obase + 1 * 512 + d] = f2bf((a10 * v0 + a11 * v1 + a12 * v2 + a13 * v3) * n1);
    concat[obase + 2 * 512 + d] = f2bf((a20 * v0 + a21 * v1 + a22 * v2 + a23 * v3) * n2);
    concat[obase + 3 * 512 + d] = f2bf((a30 * v0 + a31 * v1 + a32 * v2 + a33 * v3) * n3);
  }
}

// ---------------- launch ----------------
extern "C" void kernel_launch(void* const* d_in, const int* in_sizes, int n_in,
                              void* d_out, int out_size, void* d_ws, size_t ws_size,
                              hipStream_t stream) {
  (void)in_sizes; (void)n_in; (void)out_size; (void)ws_size;
  const float* query = (const float*)d_in[0];
  const float* key   = (const float*)d_in[1];
  const float* value = (const float*)d_in[2];
  // d_in[3] = mask (unused by the reference computation)
  const float* Wq = (const float*)d_in[4];
  const float* bq = (const float*)d_in[5];
  const float* Wk = (const float*)d_in[6];
  const float* bk = (const float*)d_in[7];
  const float* Wv = (const float*)d_in[8];
  const float* bv = (const float*)d_in[9];
  const float* Wo = (const float*)d_in[10];
  const float* bo = (const float*)d_in[11];
  const float* proj = (const float*)d_in[12];
  float* out = (float*)d_out;

  char* w = (char*)d_ws;
  size_t o = 0;
  auto take = [&](size_t b) { void* p = w + o; o += (b + 255) & ~(size_t)255; return p; };
  u16* Wqt   = (u16*)take(2097152);
  u16* Wkt   = (u16*)take(2097152);
  u16* Wvt   = (u16*)take(2097152);
  u16* Wot   = (u16*)take(2097152);
  u16* projb = (u16*)take(262144);
  u16* Qb    = (u16*)take(33554432);    // 32768 x 512 bf16
  u16* Kb    = (u16*)take(33554432);
  u16* Vb    = (u16*)take(33554432);
  float* qd  = (float*)take(33554432);  // 32768 x 256 f32
  float* kd  = (float*)take(33554432);
  u16* concat = (u16*)take(33554432);   // 16384 x 1024 bf16
  float* diagq    = (float*)take(131072);
  float* diagk    = (float*)take(131072);
  unsigned* mxkE  = (unsigned*)take(64);
  // peak ws use ~201 MB

  hipMemsetAsync(mxkE, 0, 64, stream);   // enc(-inf) = 0; replay-idempotent

  transpose4_kernel<<<dim3(32, 32, 4), dim3(32, 8), 0, stream>>>(Wq, Wk, Wv, Wo,
                                                                 Wqt, Wkt, Wvt, Wot);
  projcvt_kernel<<<128, 256, 0, stream>>>((const float4*)proj, (ushort4*)projb);

  // QKV projections: fp32 A fused conversion, bm on x for XCD L2 locality.
  gemm_bt_kernel<true, true, 0><<<dim3(128, 8), 512, 0, stream>>>(
      query, Wqt, Qb, bq, 1024, 1024, nullptr, nullptr);
  gemm_bt_kernel<true, true, 0><<<dim3(128, 8), 512, 0, stream>>>(
      key,   Wkt, Kb, bk, 1024, 1024, nullptr, nullptr);
  gemm_bt_kernel<true, true, 0><<<dim3(128, 8), 512, 0, stream>>>(
      value, Wvt, Vb, bv, 1024, 1024, nullptr, nullptr);

  // feature projections; diag fused (MODE1/2), k-max fused (MODE2).
  gemm_bt_kernel<false, false, 1><<<dim3(256, 2), 512, 0, stream>>>(
      Qb, projb, qd, nullptr, 512, 256, diagq, nullptr);
  gemm_bt_kernel<false, false, 2><<<dim3(256, 2), 512, 0, stream>>>(
      Kb, projb, kd, nullptr, 512, 256, diagk, mxkE);

  attn_kernel<<<8192, 256, 0, stream>>>(qd, kd, diagq, diagk, mxkE, Vb, concat);

  gemm_bt_kernel<false, false, 0><<<dim3(128, 8), 512, 0, stream>>>(
      concat, Wot, out, bo, 1024, 1024, nullptr, nullptr);
}